// Round 9
// baseline (1141.754 us; speedup 1.0000x reference)
//
#include <hip/hip_runtime.h>
#include <stdint.h>

#define T_    16
#define N_    2048
#define CAP_  96
#define LOG2E 1.44269504f

typedef float v4 __attribute__((ext_vector_type(4)));
typedef float f32x4 __attribute__((ext_vector_type(4)));
typedef _Float16 f16x8 __attribute__((ext_vector_type(8)));

__device__ inline float frcp(float x){
#if __has_builtin(__builtin_amdgcn_rcpf)
  return __builtin_amdgcn_rcpf(x);
#else
  return 1.0f / x;
#endif
}
// sigmoid with pre-scaled arg: xs = x*log2e
__device__ inline float fsig2(float xs){ return frcp(1.0f + __builtin_exp2f(-xs)); }
__device__ inline float fsig(float x){ return frcp(1.0f + __expf(-x)); }

// ---------------------------------------------------------------- mask build + cnt zero
__global__ __launch_bounds__(256) void k_mask(const uint8_t* __restrict__ ego_raw,
                                              float* __restrict__ m,
                                              int* __restrict__ cnt){
  __shared__ int s_int01, s_f01;
  const int tid = threadIdx.x;
  if (tid == 0){ s_int01 = 1; s_f01 = 1; }
  __syncthreads();
  const uint32_t* w = (const uint32_t*)ego_raw;
  int int01 = 1, f01 = 1;
  for (int i = tid; i < 8192; i += 256){
    uint32_t v = w[i];
    int01 &= (v <= 1u);
    f01   &= (v == 0u) || (v == 0x3F800000u);
  }
  if (!int01) atomicAnd(&s_int01, 0);
  if (!f01)   atomicAnd(&s_f01, 0);
  __syncthreads();
  const int mode = s_int01 ? 0 : (s_f01 ? 1 : 2); // 0:int32 1:f32 2:byte
  const int base = blockIdx.x * 2048;
  for (int q = tid; q < 2048; q += 256){
    int i = base + q;
    int t = i >> 11, n = i & 2047, b = n >> 8, j = n & 255;
    int src = (b*T_ + t)*256 + j;
    float val;
    if (mode == 0)      val = (((const int32_t*)ego_raw)[src] != 0)   ? 1.f : 0.f;
    else if (mode == 1) val = (((const float*)ego_raw)[src]  != 0.f)  ? 1.f : 0.f;
    else                val = (ego_raw[src] != 0)                     ? 1.f : 0.f;
    m[i] = val;
    cnt[i] = 0;
  }
}

// ---------------------------------------------------------------- sparsify adj into CSC lists
__global__ __launch_bounds__(256) void k_sparsify(const float* __restrict__ adj,
                                                  int* __restrict__ cnt,
                                                  uint16_t* __restrict__ idx){
  const int bx = blockIdx.x;           // 1024 blocks
  const int t  = bx >> 6;              // 0..15
  const int sg = bx & 63;              // 0..63, 32 s-rows each
  const int tid = threadIdx.x;
  const int tcol = t << 11;
  const float4* base4 = (const float4*)(adj + ((size_t)t << 22));
  for (int sr = 0; sr < 32; sr++){
    int s = (sg << 5) + sr;
    const float4* row4 = base4 + ((size_t)s << 9);
    #pragma unroll
    for (int ii = 0; ii < 2; ii++){
      float4 v = row4[(ii << 8) + tid];
      int d = ((ii << 8) + tid) << 2;
      if (v.x != 0.f){ int p = atomicAdd(&cnt[tcol+d  ],1); if (p<CAP_) idx[(size_t)(tcol+d  )*CAP_+p]=(uint16_t)s; }
      if (v.y != 0.f){ int p = atomicAdd(&cnt[tcol+d+1],1); if (p<CAP_) idx[(size_t)(tcol+d+1)*CAP_+p]=(uint16_t)s; }
      if (v.z != 0.f){ int p = atomicAdd(&cnt[tcol+d+2],1); if (p<CAP_) idx[(size_t)(tcol+d+2)*CAP_+p]=(uint16_t)s; }
      if (v.w != 0.f){ int p = atomicAdd(&cnt[tcol+d+3],1); if (p<CAP_) idx[(size_t)(tcol+d+3)*CAP_+p]=(uint16_t)s; }
    }
  }
}

// ---------------------------------------------------------------- dinv (batched idx loads)
__global__ __launch_bounds__(256) void k_dinv(const int* __restrict__ cnt,
                                              const uint16_t* __restrict__ idx,
                                              const float* __restrict__ m,
                                              float* __restrict__ dinv){
  const int col = blockIdx.x*256 + threadIdx.x;
  int c = cnt[col]; if (c > CAP_) c = CAP_;
  const int tbase = col & ~2047;
  const uint16_t* lst = idx + (size_t)col*CAP_;
  float s = 1.0f;                       // self-loop
  int i = 0;
  for (; i + 4 <= c; i += 4){
    ushort4 s4 = *(const ushort4*)(lst + i);       // one 8B load → 4 independent gathers
    s += (m[tbase+s4.x] + m[tbase+s4.y]) + (m[tbase+s4.z] + m[tbase+s4.w]);
  }
  for (; i < c; i++) s += m[tbase + lst[i]];
  dinv[col] = (m[col] > 0.5f) ? rsqrtf(s) : 0.f;
}

// ---------------------------------------------------------------- layer 1 fused (batched gathers)
__global__ __launch_bounds__(256) void k_gcn1(const float* __restrict__ x,
                                              const float* __restrict__ W1,
                                              const float* __restrict__ b1,
                                              const int* __restrict__ cnt,
                                              const uint16_t* __restrict__ idx,
                                              const float* __restrict__ dinv,
                                              float* __restrict__ h1){
  const int col = blockIdx.x*4 + (threadIdx.x >> 6);
  const int lane = threadIdx.x & 63;
  int c = cnt[col]; if (c > CAP_) c = CAP_;
  const int tbase = col & ~2047;
  const uint16_t* lst = idx + (size_t)col*CAP_;
  const float w1a = W1[lane], w1b = W1[64 + lane];
  const float2* x2 = (const float2*)x;
  float2 xs = x2[col];
  float acc = dinv[col]*(xs.x*w1a + xs.y*w1b);     // self-loop
  int i = 0;
  for (; i + 4 <= c; i += 4){
    ushort4 s4 = *(const ushort4*)(lst + i);
    int sa = tbase+s4.x, sb = tbase+s4.y, sc = tbase+s4.z, sd = tbase+s4.w;
    float da = dinv[sa], db = dinv[sb], dc = dinv[sc], dd = dinv[sd];
    float2 xa = x2[sa], xb = x2[sb], xc = x2[sc], xd = x2[sd];
    acc += da*(xa.x*w1a + xa.y*w1b) + db*(xb.x*w1a + xb.y*w1b)
         + dc*(xc.x*w1a + xc.y*w1b) + dd*(xd.x*w1a + xd.y*w1b);
  }
  for (; i < c; i++){
    int s = tbase + lst[i];
    float2 xv = x2[s];
    acc += dinv[s]*(xv.x*w1a + xv.y*w1b);
  }
  float y = dinv[col]*acc + b1[lane];
  h1[(size_t)col*64 + lane] = fmaxf(y, 0.f);
}

// ---------------------------------------------------------------- v2 = dinv * (h1 @ W2)
__global__ __launch_bounds__(256) void k_v2(const float* __restrict__ h1,
                                            const float* __restrict__ W2,
                                            const float* __restrict__ dinv,
                                            float* __restrict__ v2){
  const int gid = blockIdx.x*256 + threadIdx.x;   // node*64 + hp
  const int hp = gid & 63, node = gid >> 6;
  const float* row = h1 + (size_t)node*64;
  float s = 0.f;
  #pragma unroll 8
  for (int h = 0; h < 64; h++) s += row[h]*W2[h*64 + hp];
  v2[gid] = dinv[node]*s;
}

// ---------------------------------------------------------------- layer 2 aggregation (batched gathers)
__global__ __launch_bounds__(256) void k_agg2(const float* __restrict__ v,
                                              const int* __restrict__ cnt,
                                              const uint16_t* __restrict__ idx,
                                              const float* __restrict__ dinv,
                                              const float* __restrict__ m,
                                              const float* __restrict__ b2,
                                              float* __restrict__ h2){
  const int col = blockIdx.x*4 + (threadIdx.x >> 6);
  const int lane = threadIdx.x & 63;
  int c = cnt[col]; if (c > CAP_) c = CAP_;
  const int tbase = col & ~2047;
  const uint16_t* lst = idx + (size_t)col*CAP_;
  float acc = v[(size_t)col*64 + lane];            // self-loop
  int i = 0;
  for (; i + 4 <= c; i += 4){
    ushort4 s4 = *(const ushort4*)(lst + i);
    float a0 = v[((size_t)tbase + s4.x)*64 + lane];
    float a1 = v[((size_t)tbase + s4.y)*64 + lane];
    float a2 = v[((size_t)tbase + s4.z)*64 + lane];
    float a3 = v[((size_t)tbase + s4.w)*64 + lane];
    acc += (a0 + a1) + (a2 + a3);
  }
  for (; i < c; i++) acc += v[((size_t)tbase + lst[i])*64 + lane];
  float y = dinv[col]*acc + b2[lane];
  h2[(size_t)col*64 + lane] = m[col]*y;
}

// ---------------------------------------------------------------- P4[tn][j][gate], PRE-SCALED by log2e
__global__ __attribute__((amdgpu_flat_work_group_size(256,256), amdgpu_waves_per_eu(1)))
void k_lstmpre(const float* __restrict__ h2,
               const float* __restrict__ Wih,
               const float* __restrict__ bih,
               const float* __restrict__ bhh,
               float* __restrict__ P4){
  const int tid = threadIdx.x;
  const int j = tid & 127;                         // gate row 0..127
  const int half = tid >> 7;                       // 0/1
  const int tn0 = blockIdx.x*64 + half*32;
  const v4* wsrc = (const v4*)(Wih + j*64);
#define LWP(Q) v4 u##Q = wsrc[Q]; asm("" : "+v"(u##Q));
  LWP(0)  LWP(1)  LWP(2)  LWP(3)  LWP(4)  LWP(5)  LWP(6)  LWP(7)
  LWP(8)  LWP(9)  LWP(10) LWP(11) LWP(12) LWP(13) LWP(14) LWP(15)
#undef LWP
  const float bj = bih[j] + bhh[j];
  const int dst = (j & 31)*4 + (j >> 5);           // interleaved {i,f,g,o} per jj
  for (int r = 0; r < 32; r++){
    int tn = tn0 + r;
    const v4* row = (const v4*)(h2 + (size_t)tn*64);
    float a0 = bj, a1 = 0.f, a2 = 0.f, a3 = 0.f;
#define ACC(Q){ v4 hv = row[Q]; \
    a0 = fmaf(u##Q.x, hv.x, a0); a1 = fmaf(u##Q.y, hv.y, a1); \
    a2 = fmaf(u##Q.z, hv.z, a2); a3 = fmaf(u##Q.w, hv.w, a3); }
    ACC(0)  ACC(1)  ACC(2)  ACC(3)  ACC(4)  ACC(5)  ACC(6)  ACC(7)
    ACC(8)  ACC(9)  ACC(10) ACC(11) ACC(12) ACC(13) ACC(14) ACC(15)
#undef ACC
    P4[(size_t)tn*128 + dst] = ((a0 + a1) + (a2 + a3)) * LOG2E;   // scaled domain
  }
}

// ---------------------------------------------------------------- LSTM scan: 16 chains, 1 wave each
// R8 MFMA structure + micro-cuts: Whh/P4 pre-scaled by log2e (exp2 with free
// neg-modifier replaces exp, -5 instr/step), pointer-increment addressing,
// unclamped distance-2 prefetch (1KB overread past P4 stays inside ws).
__global__ __attribute__((amdgpu_flat_work_group_size(64,64), amdgpu_waves_per_eu(1,1)))
void k_lstm(const float* __restrict__ P4,
            const float* __restrict__ Whh,
            float* __restrict__ L64){
  const int t = blockIdx.x;       // chain 0..15
  const int l = threadIdx.x;      // 0..63
  const int c4 = l & 15, q = l >> 4;
  const int j = l & 31;
  // B-frags (loop-invariant, scaled by log2e), named + pinned
#define LB(B) f16x8 b##B; { const float* wr = Whh + (size_t)(16*B + c4)*32 + 8*q; \
    f16x8 tmp; tmp[0]=(_Float16)(wr[0]*LOG2E); tmp[1]=(_Float16)(wr[1]*LOG2E); \
    tmp[2]=(_Float16)(wr[2]*LOG2E); tmp[3]=(_Float16)(wr[3]*LOG2E); \
    tmp[4]=(_Float16)(wr[4]*LOG2E); tmp[5]=(_Float16)(wr[5]*LOG2E); \
    tmp[6]=(_Float16)(wr[6]*LOG2E); tmp[7]=(_Float16)(wr[7]*LOG2E); b##B = tmp; } \
    asm("" : "+v"(b##B));
  LB(0) LB(1) LB(2) LB(3) LB(4) LB(5) LB(6) LB(7)
#undef LB
  __shared__ __align__(16) _Float16 hs[32];
  hs[j] = (_Float16)0.f;          // all lanes; duplicates write same value
  const float4* Pt = (const float4*)P4 + (size_t)t*N_*32 + j;
  const float4* Pp2 = Pt + 64;    // n+2 prefetch cursor
  float* Lt = L64 + (size_t)t*N_*64 + l;
  float c = 0.f;
  const f32x4 zero = {0.f, 0.f, 0.f, 0.f};
  const bool hiq = (l & 16) != 0;
  float4 p0 = Pt[0], p1 = Pt[32];
  for (int n = 0; n < N_; n++){
    float4 cur = p0; p0 = p1;
    p1 = Pp2[0]; Pp2 += 32;                        // unclamped; ≤1KB overread in ws
    f16x8 af = *(const f16x8*)(hs + 8*q);          // ds_read_b128, h[8q..8q+7]
    f32x4 d0 = __builtin_amdgcn_mfma_f32_16x16x32_f16(af, b0, zero, 0, 0, 0);
    f32x4 d1 = __builtin_amdgcn_mfma_f32_16x16x32_f16(af, b1, zero, 0, 0, 0);
    f32x4 d2 = __builtin_amdgcn_mfma_f32_16x16x32_f16(af, b2, zero, 0, 0, 0);
    f32x4 d3 = __builtin_amdgcn_mfma_f32_16x16x32_f16(af, b3, zero, 0, 0, 0);
    f32x4 d4 = __builtin_amdgcn_mfma_f32_16x16x32_f16(af, b4, zero, 0, 0, 0);
    f32x4 d5 = __builtin_amdgcn_mfma_f32_16x16x32_f16(af, b5, zero, 0, 0, 0);
    f32x4 d6 = __builtin_amdgcn_mfma_f32_16x16x32_f16(af, b6, zero, 0, 0, 0);
    f32x4 d7 = __builtin_amdgcn_mfma_f32_16x16x32_f16(af, b7, zero, 0, 0, 0);
    float gi = cur.x + (hiq ? d1[0] : d0[0]);      // scaled domain
    float gf = cur.y + (hiq ? d3[0] : d2[0]);
    float gg = cur.z + (hiq ? d5[0] : d4[0]);
    float go = cur.w + (hiq ? d7[0] : d6[0]);
    float iv = fsig2(gi);
    float fv = fsig2(gf);
    float gv = fmaf(2.0f, fsig2(2.0f*gg), -1.0f);  // tanh (scaled arg)
    float ov = fsig2(go);
    c = fmaf(fv, c, iv*gv);
    float th = fmaf(2.0f, frcp(1.0f + __builtin_exp2f(-2.88539008f*c)), -1.0f); // tanh(c)
    float hn = ov*th;
    hs[j] = (_Float16)hn;                          // ds_write_b16 (dups identical)
    *Lt = hn; Lt += 64;                            // full-wave store
  }
}

// ---------------------------------------------------------------- scores[t*2048+n] = lstm[t,n,:]@Wa
__global__ __launch_bounds__(256) void k_score(const float* __restrict__ L64,
                                               const float* __restrict__ Wa,
                                               float* __restrict__ scores){
  const int gid = blockIdx.x*256 + threadIdx.x;   // t*2048 + n, 32768 total
  const float4* row = (const float4*)(L64 + (size_t)gid*64);
  const float4* wa4 = (const float4*)Wa;
  float s = 0.f;
  #pragma unroll
  for (int qq = 0; qq < 8; qq++){
    float4 hv = row[qq], wv = wa4[qq];
    s += hv.x*wv.x + hv.y*wv.y + hv.z*wv.z + hv.w*wv.w;
  }
  scores[gid] = s;
}

// ---------------------------------------------------------------- softmax attention pool
__global__ __launch_bounds__(256) void k_attn(const float* __restrict__ scores,
                                              const float* __restrict__ L64,
                                              float* __restrict__ out){
  const int gid = blockIdx.x*256 + threadIdx.x;   // n*32 + k
  const int k = gid & 31, n = gid >> 5;
  float sc[16]; float mx = -1e30f;
  #pragma unroll
  for (int t = 0; t < 16; t++){ float v = scores[(t << 11) + n]; sc[t] = v; mx = fmaxf(mx, v); }
  float sum = 0.f;
  #pragma unroll
  for (int t = 0; t < 16; t++){ float e = __expf(sc[t] - mx); sc[t] = e; sum += e; }
  const float inv = frcp(sum);
  float acc = 0.f;
  #pragma unroll
  for (int t = 0; t < 16; t++) acc += sc[t]*L64[((size_t)((t << 11) + n))*64 + k];
  out[gid] = acc*inv;
}

// ---------------------------------------------------------------- launch
extern "C" void kernel_launch(void* const* d_in, const int* in_sizes, int n_in,
                              void* d_out, int out_size, void* d_ws, size_t ws_size,
                              hipStream_t stream){
  (void)in_sizes; (void)n_in; (void)out_size; (void)ws_size;
  const float*   x   = (const float*)d_in[0];
  const float*   adj = (const float*)d_in[1];
  const uint8_t* ego = (const uint8_t*)d_in[2];
  const float*   W1  = (const float*)d_in[3];
  const float*   b1  = (const float*)d_in[4];
  const float*   W2  = (const float*)d_in[5];
  const float*   b2  = (const float*)d_in[6];
  const float*   Wih = (const float*)d_in[7];
  const float*   Whh = (const float*)d_in[8];
  const float*   bih = (const float*)d_in[9];
  const float*   bhh = (const float*)d_in[10];
  const float*   Wa  = (const float*)d_in[11];
  // d_in[12] = ba: softmax is shift-invariant, unused
  float* out = (float*)d_out;
  char* ws = (char*)d_ws;

  float*    m      = (float*)(ws);                  // 128 KB
  float*    dinv   = (float*)(ws + 131072);         // 128 KB
  int*      cnt    = (int*)  (ws + 262144);         // 128 KB
  uint16_t* idx    = (uint16_t*)(ws + 393216);      // 6 MB
  float*    v      = (float*)(ws + 6684672);        // 8 MB   (v2; later reused as L64)
  float*    h      = (float*)(ws + 15073280);       // 8 MB   (h1 then h2; later scores)
  float*    P4     = (float*)(ws + 23461888);       // 16 MB
  float*    L64    = v;                             // v dead after k_agg2
  float*    scores = h;                             // h dead after k_lstmpre

  k_mask    <<<16,    256, 0, stream>>>(ego, m, cnt);
  k_sparsify<<<1024,  256, 0, stream>>>(adj, cnt, idx);
  k_dinv    <<<128,   256, 0, stream>>>(cnt, idx, m, dinv);
  k_gcn1    <<<8192,  256, 0, stream>>>(x, W1, b1, cnt, idx, dinv, h);
  k_v2      <<<8192,  256, 0, stream>>>(h, W2, dinv, v);
  k_agg2    <<<8192,  256, 0, stream>>>(v, cnt, idx, dinv, m, b2, h);
  k_lstmpre <<<512,   256, 0, stream>>>(h, Wih, bih, bhh, P4);
  k_lstm    <<<16,    64,  0, stream>>>(P4, Whh, L64);
  k_score   <<<128,   256, 0, stream>>>(L64, Wa, scores);
  k_attn    <<<256,   256, 0, stream>>>(scores, L64, out);
}

// Round 10
// 1098.834 us; speedup vs baseline: 1.0391x; 1.0391x over previous
//
#include <hip/hip_runtime.h>
#include <stdint.h>

#define T_    16
#define N_    2048
#define CAP_  96

typedef float v4 __attribute__((ext_vector_type(4)));
typedef float f32x4 __attribute__((ext_vector_type(4)));
typedef _Float16 f16x8 __attribute__((ext_vector_type(8)));

__device__ inline float frcp(float x){
#if __has_builtin(__builtin_amdgcn_rcpf)
  return __builtin_amdgcn_rcpf(x);
#else
  return 1.0f / x;
#endif
}
__device__ inline float fsig(float x){ return frcp(1.0f + __expf(-x)); }

// ---------------------------------------------------------------- mask build + cnt zero
__global__ __launch_bounds__(256) void k_mask(const uint8_t* __restrict__ ego_raw,
                                              float* __restrict__ m,
                                              int* __restrict__ cnt){
  __shared__ int s_int01, s_f01;
  const int tid = threadIdx.x;
  if (tid == 0){ s_int01 = 1; s_f01 = 1; }
  __syncthreads();
  const uint32_t* w = (const uint32_t*)ego_raw;
  int int01 = 1, f01 = 1;
  for (int i = tid; i < 8192; i += 256){
    uint32_t v = w[i];
    int01 &= (v <= 1u);
    f01   &= (v == 0u) || (v == 0x3F800000u);
  }
  if (!int01) atomicAnd(&s_int01, 0);
  if (!f01)   atomicAnd(&s_f01, 0);
  __syncthreads();
  const int mode = s_int01 ? 0 : (s_f01 ? 1 : 2); // 0:int32 1:f32 2:byte
  const int base = blockIdx.x * 2048;
  for (int q = tid; q < 2048; q += 256){
    int i = base + q;
    int t = i >> 11, n = i & 2047, b = n >> 8, j = n & 255;
    int src = (b*T_ + t)*256 + j;
    float val;
    if (mode == 0)      val = (((const int32_t*)ego_raw)[src] != 0)   ? 1.f : 0.f;
    else if (mode == 1) val = (((const float*)ego_raw)[src]  != 0.f)  ? 1.f : 0.f;
    else                val = (ego_raw[src] != 0)                     ? 1.f : 0.f;
    m[i] = val;
    cnt[i] = 0;
  }
}

// ---------------------------------------------------------------- sparsify adj into CSC lists
__global__ __launch_bounds__(256) void k_sparsify(const float* __restrict__ adj,
                                                  int* __restrict__ cnt,
                                                  uint16_t* __restrict__ idx){
  const int bx = blockIdx.x;           // 1024 blocks
  const int t  = bx >> 6;              // 0..15
  const int sg = bx & 63;              // 0..63, 32 s-rows each
  const int tid = threadIdx.x;
  const int tcol = t << 11;
  const float4* base4 = (const float4*)(adj + ((size_t)t << 22));
  for (int sr = 0; sr < 32; sr++){
    int s = (sg << 5) + sr;
    const float4* row4 = base4 + ((size_t)s << 9);
    #pragma unroll
    for (int ii = 0; ii < 2; ii++){
      float4 v = row4[(ii << 8) + tid];
      int d = ((ii << 8) + tid) << 2;
      if (v.x != 0.f){ int p = atomicAdd(&cnt[tcol+d  ],1); if (p<CAP_) idx[(size_t)(tcol+d  )*CAP_+p]=(uint16_t)s; }
      if (v.y != 0.f){ int p = atomicAdd(&cnt[tcol+d+1],1); if (p<CAP_) idx[(size_t)(tcol+d+1)*CAP_+p]=(uint16_t)s; }
      if (v.z != 0.f){ int p = atomicAdd(&cnt[tcol+d+2],1); if (p<CAP_) idx[(size_t)(tcol+d+2)*CAP_+p]=(uint16_t)s; }
      if (v.w != 0.f){ int p = atomicAdd(&cnt[tcol+d+3],1); if (p<CAP_) idx[(size_t)(tcol+d+3)*CAP_+p]=(uint16_t)s; }
    }
  }
}

// ---------------------------------------------------------------- dinv (batched idx loads)
__global__ __launch_bounds__(256) void k_dinv(const int* __restrict__ cnt,
                                              const uint16_t* __restrict__ idx,
                                              const float* __restrict__ m,
                                              float* __restrict__ dinv){
  const int col = blockIdx.x*256 + threadIdx.x;
  int c = cnt[col]; if (c > CAP_) c = CAP_;
  const int tbase = col & ~2047;
  const uint16_t* lst = idx + (size_t)col*CAP_;
  float s = 1.0f;                       // self-loop
  int i = 0;
  for (; i + 4 <= c; i += 4){
    ushort4 s4 = *(const ushort4*)(lst + i);
    s += (m[tbase+s4.x] + m[tbase+s4.y]) + (m[tbase+s4.z] + m[tbase+s4.w]);
  }
  for (; i < c; i++) s += m[tbase + lst[i]];
  dinv[col] = (m[col] > 0.5f) ? rsqrtf(s) : 0.f;
}

// ---------------------------------------------------------------- FUSED layer1 + v2
// h1 = relu(dinv*Σ dinv_s*(x_s@W1) + b1) lives only in LDS (1 KB);
// v2 = dinv * (h1 @ W2) written to global. Kills 16 MB of h1 round-trip.
__global__ __launch_bounds__(256) void k_gcn1v2(const float* __restrict__ x,
                                                const float* __restrict__ W1,
                                                const float* __restrict__ b1,
                                                const float* __restrict__ W2,
                                                const int* __restrict__ cnt,
                                                const uint16_t* __restrict__ idx,
                                                const float* __restrict__ dinv,
                                                float* __restrict__ v2){
  __shared__ float h1s[256];            // 4 cols × 64
  const int col4 = threadIdx.x >> 6;
  const int col = blockIdx.x*4 + col4;
  const int lane = threadIdx.x & 63;
  int c = cnt[col]; if (c > CAP_) c = CAP_;
  const int tbase = col & ~2047;
  const uint16_t* lst = idx + (size_t)col*CAP_;
  const float w1a = W1[lane], w1b = W1[64 + lane];
  const float2* x2 = (const float2*)x;
  float2 xs = x2[col];
  float acc = dinv[col]*(xs.x*w1a + xs.y*w1b);     // self-loop
  int i = 0;
  for (; i + 4 <= c; i += 4){
    ushort4 s4 = *(const ushort4*)(lst + i);
    int sa = tbase+s4.x, sb = tbase+s4.y, sc = tbase+s4.z, sd = tbase+s4.w;
    float da = dinv[sa], db = dinv[sb], dc = dinv[sc], dd = dinv[sd];
    float2 xa = x2[sa], xb = x2[sb], xc = x2[sc], xd = x2[sd];
    acc += da*(xa.x*w1a + xa.y*w1b) + db*(xb.x*w1a + xb.y*w1b)
         + dc*(xc.x*w1a + xc.y*w1b) + dd*(xd.x*w1a + xd.y*w1b);
  }
  for (; i < c; i++){
    int s = tbase + lst[i];
    float2 xv = x2[s];
    acc += dinv[s]*(xv.x*w1a + xv.y*w1b);
  }
  float y = dinv[col]*acc + b1[lane];
  h1s[threadIdx.x] = fmaxf(y, 0.f);
  __syncthreads();
  // v2 phase: thread (col4, hp=lane)
  const float* hrow = h1s + col4*64;               // broadcast LDS reads
  float s = 0.f;
  #pragma unroll 8
  for (int h = 0; h < 64; h++) s += hrow[h]*W2[h*64 + lane];
  v2[(size_t)col*64 + lane] = dinv[col]*s;
}

// ---------------------------------------------------------------- FUSED layer2 agg + lstmpre
// h2 = m*(dinv*Σ v2 + b2) lives only in LDS; P4[tn][jj][gate] written direct.
__global__ __launch_bounds__(256) void k_agg2pre(const float* __restrict__ v,
                                                 const int* __restrict__ cnt,
                                                 const uint16_t* __restrict__ idx,
                                                 const float* __restrict__ dinv,
                                                 const float* __restrict__ m,
                                                 const float* __restrict__ b2,
                                                 const float* __restrict__ Wih,
                                                 const float* __restrict__ bih,
                                                 const float* __restrict__ bhh,
                                                 float* __restrict__ P4){
  __shared__ float h2s[256];            // 4 cols × 64
  const int col4 = threadIdx.x >> 6;
  const int col = blockIdx.x*4 + col4;
  const int lane = threadIdx.x & 63;
  int c = cnt[col]; if (c > CAP_) c = CAP_;
  const int tbase = col & ~2047;
  const uint16_t* lst = idx + (size_t)col*CAP_;
  float acc = v[(size_t)col*64 + lane];            // self-loop
  int i = 0;
  for (; i + 4 <= c; i += 4){
    ushort4 s4 = *(const ushort4*)(lst + i);
    float a0 = v[((size_t)tbase + s4.x)*64 + lane];
    float a1 = v[((size_t)tbase + s4.y)*64 + lane];
    float a2 = v[((size_t)tbase + s4.z)*64 + lane];
    float a3 = v[((size_t)tbase + s4.w)*64 + lane];
    acc += (a0 + a1) + (a2 + a3);
  }
  for (; i < c; i++) acc += v[((size_t)tbase + lst[i])*64 + lane];
  float y = dinv[col]*acc + b2[lane];
  h2s[threadIdx.x] = m[col]*y;
  __syncthreads();
  // lstmpre phase: 512 outputs (4 cols × 128 j), 2 per thread
  #pragma unroll
  for (int o = threadIdx.x; o < 512; o += 256){
    const int cc = o >> 7;                         // 0..3
    const int j  = o & 127;
    const int tn = blockIdx.x*4 + cc;
    const v4* hrow = (const v4*)(h2s + cc*64);     // broadcast LDS b128 reads
    const v4* wr = (const v4*)(Wih + j*64);
    float a0 = bih[j] + bhh[j], a1 = 0.f, a2 = 0.f, a3 = 0.f;
    #pragma unroll
    for (int q = 0; q < 16; q++){
      v4 hv = hrow[q], wv = wr[q];
      a0 = fmaf(wv.x, hv.x, a0);
      a1 = fmaf(wv.y, hv.y, a1);
      a2 = fmaf(wv.z, hv.z, a2);
      a3 = fmaf(wv.w, hv.w, a3);
    }
    const int dst = (j & 31)*4 + (j >> 5);         // interleaved {i,f,g,o}
    P4[(size_t)tn*128 + dst] = (a0 + a1) + (a2 + a3);
  }
}

// ---------------------------------------------------------------- LSTM scan: 16 chains, 1 wave each (exact R8)
__global__ __attribute__((amdgpu_flat_work_group_size(64,64), amdgpu_waves_per_eu(1,1)))
void k_lstm(const float* __restrict__ P4,
            const float* __restrict__ Whh,
            float* __restrict__ L64){
  const int t = blockIdx.x;       // chain 0..15
  const int l = threadIdx.x;      // 0..63
  const int c4 = l & 15, q = l >> 4;
  const int j = l & 31;
#define LB(B) f16x8 b##B; { const float* wr = Whh + (size_t)(16*B + c4)*32 + 8*q; \
    f16x8 tmp; tmp[0]=(_Float16)wr[0]; tmp[1]=(_Float16)wr[1]; tmp[2]=(_Float16)wr[2]; \
    tmp[3]=(_Float16)wr[3]; tmp[4]=(_Float16)wr[4]; tmp[5]=(_Float16)wr[5]; \
    tmp[6]=(_Float16)wr[6]; tmp[7]=(_Float16)wr[7]; b##B = tmp; } asm("" : "+v"(b##B));
  LB(0) LB(1) LB(2) LB(3) LB(4) LB(5) LB(6) LB(7)
#undef LB
  __shared__ __align__(16) _Float16 hs[32];
  hs[j] = (_Float16)0.f;
  const float4* Pt = (const float4*)P4 + (size_t)t*N_*32 + j;
  float* Lt = L64 + (size_t)t*N_*64;
  float c = 0.f;
  const f32x4 zero = {0.f, 0.f, 0.f, 0.f};
  const bool hiq = (l & 16) != 0;
  float4 p0 = Pt[0], p1 = Pt[32];
  for (int n = 0; n < N_; n++){
    float4 cur = p0; p0 = p1;
    int np = (n + 2 < N_) ? (n + 2) : (N_ - 1);
    p1 = Pt[(size_t)np*32];
    f16x8 af = *(const f16x8*)(hs + 8*q);          // ds_read_b128
    f32x4 d0 = __builtin_amdgcn_mfma_f32_16x16x32_f16(af, b0, zero, 0, 0, 0);
    f32x4 d1 = __builtin_amdgcn_mfma_f32_16x16x32_f16(af, b1, zero, 0, 0, 0);
    f32x4 d2 = __builtin_amdgcn_mfma_f32_16x16x32_f16(af, b2, zero, 0, 0, 0);
    f32x4 d3 = __builtin_amdgcn_mfma_f32_16x16x32_f16(af, b3, zero, 0, 0, 0);
    f32x4 d4 = __builtin_amdgcn_mfma_f32_16x16x32_f16(af, b4, zero, 0, 0, 0);
    f32x4 d5 = __builtin_amdgcn_mfma_f32_16x16x32_f16(af, b5, zero, 0, 0, 0);
    f32x4 d6 = __builtin_amdgcn_mfma_f32_16x16x32_f16(af, b6, zero, 0, 0, 0);
    f32x4 d7 = __builtin_amdgcn_mfma_f32_16x16x32_f16(af, b7, zero, 0, 0, 0);
    float gi = cur.x + (hiq ? d1[0] : d0[0]);
    float gf = cur.y + (hiq ? d3[0] : d2[0]);
    float gg = cur.z + (hiq ? d5[0] : d4[0]);
    float go = cur.w + (hiq ? d7[0] : d6[0]);
    float iv = fsig(gi);
    float fv = fsig(gf);
    float gv = fmaf(2.0f, fsig(2.0f*gg), -1.0f);   // tanh
    float ov = fsig(go);
    c = fmaf(fv, c, iv*gv);
    float th = fmaf(2.0f, fsig(2.0f*c), -1.0f);    // tanh(c)
    float hn = ov*th;
    hs[j] = (_Float16)hn;                          // ds_write_b16
    Lt[n*64 + l] = hn;                             // full-wave store
  }
}

// ---------------------------------------------------------------- FUSED score + softmax attention pool
// 8 nodes/block; threads (sub 0..7, k 0..31). Score phase: k<16 → t=k.
__global__ __launch_bounds__(256) void k_attn(const float* __restrict__ L64,
                                              const float* __restrict__ Wa,
                                              float* __restrict__ out){
  __shared__ float sLDS[128];           // 8 nodes × 16 scores
  const int tid = threadIdx.x;
  const int sub = tid >> 5, k = tid & 31;
  const int n = blockIdx.x*8 + sub;
  if (k < 16){
    const int t = k;
    const float4* row = (const float4*)(L64 + ((size_t)(t << 11) + n)*64);
    const float4* wa4 = (const float4*)Wa;
    float s = 0.f;
    #pragma unroll
    for (int qq = 0; qq < 8; qq++){
      float4 hv = row[qq], wv = wa4[qq];
      s += hv.x*wv.x + hv.y*wv.y + hv.z*wv.z + hv.w*wv.w;
    }
    sLDS[sub*16 + t] = s;
  }
  __syncthreads();
  float sc[16]; float mx = -1e30f;
  #pragma unroll
  for (int t = 0; t < 16; t++){ float v = sLDS[sub*16 + t]; sc[t] = v; mx = fmaxf(mx, v); }
  float sum = 0.f;
  #pragma unroll
  for (int t = 0; t < 16; t++){ float e = __expf(sc[t] - mx); sc[t] = e; sum += e; }
  const float inv = frcp(sum);
  float acc = 0.f;
  #pragma unroll
  for (int t = 0; t < 16; t++) acc += sc[t]*L64[((size_t)(t << 11) + n)*64 + k];
  out[n*32 + k] = acc*inv;
}

// ---------------------------------------------------------------- launch
extern "C" void kernel_launch(void* const* d_in, const int* in_sizes, int n_in,
                              void* d_out, int out_size, void* d_ws, size_t ws_size,
                              hipStream_t stream){
  (void)in_sizes; (void)n_in; (void)out_size; (void)ws_size;
  const float*   x   = (const float*)d_in[0];
  const float*   adj = (const float*)d_in[1];
  const uint8_t* ego = (const uint8_t*)d_in[2];
  const float*   W1  = (const float*)d_in[3];
  const float*   b1  = (const float*)d_in[4];
  const float*   W2  = (const float*)d_in[5];
  const float*   b2  = (const float*)d_in[6];
  const float*   Wih = (const float*)d_in[7];
  const float*   Whh = (const float*)d_in[8];
  const float*   bih = (const float*)d_in[9];
  const float*   bhh = (const float*)d_in[10];
  const float*   Wa  = (const float*)d_in[11];
  // d_in[12] = ba: softmax is shift-invariant, unused
  float* out = (float*)d_out;
  char* ws = (char*)d_ws;

  float*    m      = (float*)(ws);                  // 128 KB
  float*    dinv   = (float*)(ws + 131072);         // 128 KB
  int*      cnt    = (int*)  (ws + 262144);         // 128 KB
  uint16_t* idx    = (uint16_t*)(ws + 393216);      // 6 MB   (end 6,684,672)
  float*    v2     = (float*)(ws + 6684672);        // 8 MB   (v2; later reused as L64)
  float*    P4     = (float*)(ws + 15073280);       // 16 MB  (end 31,850,496)
  float*    L64    = v2;                            // v2 dead after k_agg2pre

  k_mask    <<<16,   256, 0, stream>>>(ego, m, cnt);
  k_sparsify<<<1024, 256, 0, stream>>>(adj, cnt, idx);
  k_dinv    <<<128,  256, 0, stream>>>(cnt, idx, m, dinv);
  k_gcn1v2  <<<8192, 256, 0, stream>>>(x, W1, b1, W2, cnt, idx, dinv, v2);
  k_agg2pre <<<8192, 256, 0, stream>>>(v2, cnt, idx, dinv, m, b2, Wih, bih, bhh, P4);
  k_lstm    <<<16,   64,  0, stream>>>(P4, Whh, L64);
  k_attn    <<<256,  256, 0, stream>>>(L64, Wa, out);
}

// Round 11
// 1000.840 us; speedup vs baseline: 1.1408x; 1.0979x over previous
//
#include <hip/hip_runtime.h>
#include <stdint.h>

#define T_    16
#define N_    2048
#define CAP_  96

typedef float v4 __attribute__((ext_vector_type(4)));
typedef float f32x4 __attribute__((ext_vector_type(4)));
typedef _Float16 f16x8 __attribute__((ext_vector_type(8)));

__device__ inline float frcp(float x){
#if __has_builtin(__builtin_amdgcn_rcpf)
  return __builtin_amdgcn_rcpf(x);
#else
  return 1.0f / x;
#endif
}
__device__ inline float fsig(float x){ return frcp(1.0f + __expf(-x)); }

// ---------------------------------------------------------------- mask build + cnt zero
__global__ __launch_bounds__(256) void k_mask(const uint8_t* __restrict__ ego_raw,
                                              float* __restrict__ m,
                                              int* __restrict__ cnt){
  __shared__ int s_int01, s_f01;
  const int tid = threadIdx.x;
  if (tid == 0){ s_int01 = 1; s_f01 = 1; }
  __syncthreads();
  const uint32_t* w = (const uint32_t*)ego_raw;
  int int01 = 1, f01 = 1;
  for (int i = tid; i < 8192; i += 256){
    uint32_t v = w[i];
    int01 &= (v <= 1u);
    f01   &= (v == 0u) || (v == 0x3F800000u);
  }
  if (!int01) atomicAnd(&s_int01, 0);
  if (!f01)   atomicAnd(&s_f01, 0);
  __syncthreads();
  const int mode = s_int01 ? 0 : (s_f01 ? 1 : 2); // 0:int32 1:f32 2:byte
  const int base = blockIdx.x * 2048;
  for (int q = tid; q < 2048; q += 256){
    int i = base + q;
    int t = i >> 11, n = i & 2047, b = n >> 8, j = n & 255;
    int src = (b*T_ + t)*256 + j;
    float val;
    if (mode == 0)      val = (((const int32_t*)ego_raw)[src] != 0)   ? 1.f : 0.f;
    else if (mode == 1) val = (((const float*)ego_raw)[src]  != 0.f)  ? 1.f : 0.f;
    else                val = (ego_raw[src] != 0)                     ? 1.f : 0.f;
    m[i] = val;
    cnt[i] = 0;
  }
}

// ---------------------------------------------------------------- masked sparsify
// ~50% of nodes are masked out and contribute exact zeros downstream:
// skip dead source rows entirely (halves the 268 MB adj read) and skip
// list-writes to dead columns (col-masks preloaded to registers).
// Lists then contain only live x live edges (~4x fewer atomics) and
// every listed neighbor has m==1, so dinv needs no gather.
__global__ __launch_bounds__(256) void k_sparsify(const float* __restrict__ adj,
                                                  const float* __restrict__ m,
                                                  int* __restrict__ cnt,
                                                  uint16_t* __restrict__ idx){
  const int bx = blockIdx.x;           // 1024 blocks
  const int t  = bx >> 6;              // 0..15
  const int sg = bx & 63;              // 0..63, 32 s-rows each
  const int tid = threadIdx.x;
  const int tcol = t << 11;
  const float4* base4 = (const float4*)(adj + ((size_t)t << 22));
  const int d0a = tid << 2;            // ii=0 cols
  const int d0b = (256 + tid) << 2;    // ii=1 cols
  const float4 ma = *(const float4*)(m + tcol + d0a);
  const float4 mb = *(const float4*)(m + tcol + d0b);
  for (int sr = 0; sr < 32; sr++){
    int s = (sg << 5) + sr;
    if (m[tcol + s] == 0.f) continue;  // dead source: skip row (scalar branch)
    const float4* row4 = base4 + ((size_t)s << 9);
    float4 va = row4[tid];
    float4 vb = row4[256 + tid];
    if (va.x != 0.f && ma.x != 0.f){ int p = atomicAdd(&cnt[tcol+d0a  ],1); if (p<CAP_) idx[(size_t)(tcol+d0a  )*CAP_+p]=(uint16_t)s; }
    if (va.y != 0.f && ma.y != 0.f){ int p = atomicAdd(&cnt[tcol+d0a+1],1); if (p<CAP_) idx[(size_t)(tcol+d0a+1)*CAP_+p]=(uint16_t)s; }
    if (va.z != 0.f && ma.z != 0.f){ int p = atomicAdd(&cnt[tcol+d0a+2],1); if (p<CAP_) idx[(size_t)(tcol+d0a+2)*CAP_+p]=(uint16_t)s; }
    if (va.w != 0.f && ma.w != 0.f){ int p = atomicAdd(&cnt[tcol+d0a+3],1); if (p<CAP_) idx[(size_t)(tcol+d0a+3)*CAP_+p]=(uint16_t)s; }
    if (vb.x != 0.f && mb.x != 0.f){ int p = atomicAdd(&cnt[tcol+d0b  ],1); if (p<CAP_) idx[(size_t)(tcol+d0b  )*CAP_+p]=(uint16_t)s; }
    if (vb.y != 0.f && mb.y != 0.f){ int p = atomicAdd(&cnt[tcol+d0b+1],1); if (p<CAP_) idx[(size_t)(tcol+d0b+1)*CAP_+p]=(uint16_t)s; }
    if (vb.z != 0.f && mb.z != 0.f){ int p = atomicAdd(&cnt[tcol+d0b+2],1); if (p<CAP_) idx[(size_t)(tcol+d0b+2)*CAP_+p]=(uint16_t)s; }
    if (vb.w != 0.f && mb.w != 0.f){ int p = atomicAdd(&cnt[tcol+d0b+3],1); if (p<CAP_) idx[(size_t)(tcol+d0b+3)*CAP_+p]=(uint16_t)s; }
  }
}

// ---------------------------------------------------------------- dinv (no gathers: all listed neighbors are live)
__global__ __launch_bounds__(256) void k_dinv(const int* __restrict__ cnt,
                                              const float* __restrict__ m,
                                              float* __restrict__ dinv){
  const int col = blockIdx.x*256 + threadIdx.x;
  int c = cnt[col]; if (c > CAP_) c = CAP_;
  dinv[col] = (m[col] > 0.5f) ? rsqrtf(1.0f + (float)c) : 0.f;
}

// ---------------------------------------------------------------- FUSED layer1 + v2
// h1 lives only in LDS; v2 = dinv * (h1 @ W2) to global.
__global__ __launch_bounds__(256) void k_gcn1v2(const float* __restrict__ x,
                                                const float* __restrict__ W1,
                                                const float* __restrict__ b1,
                                                const float* __restrict__ W2,
                                                const int* __restrict__ cnt,
                                                const uint16_t* __restrict__ idx,
                                                const float* __restrict__ dinv,
                                                float* __restrict__ v2){
  __shared__ float h1s[256];            // 4 cols × 64
  const int col4 = threadIdx.x >> 6;
  const int col = blockIdx.x*4 + col4;
  const int lane = threadIdx.x & 63;
  int c = cnt[col]; if (c > CAP_) c = CAP_;
  const int tbase = col & ~2047;
  const uint16_t* lst = idx + (size_t)col*CAP_;
  const float w1a = W1[lane], w1b = W1[64 + lane];
  const float2* x2 = (const float2*)x;
  float2 xs = x2[col];
  float acc = dinv[col]*(xs.x*w1a + xs.y*w1b);     // self-loop
  int i = 0;
  for (; i + 4 <= c; i += 4){
    ushort4 s4 = *(const ushort4*)(lst + i);
    int sa = tbase+s4.x, sb = tbase+s4.y, sc = tbase+s4.z, sd = tbase+s4.w;
    float da = dinv[sa], db = dinv[sb], dc = dinv[sc], dd = dinv[sd];
    float2 xa = x2[sa], xb = x2[sb], xc = x2[sc], xd = x2[sd];
    acc += da*(xa.x*w1a + xa.y*w1b) + db*(xb.x*w1a + xb.y*w1b)
         + dc*(xc.x*w1a + xc.y*w1b) + dd*(xd.x*w1a + xd.y*w1b);
  }
  for (; i < c; i++){
    int s = tbase + lst[i];
    float2 xv = x2[s];
    acc += dinv[s]*(xv.x*w1a + xv.y*w1b);
  }
  float y = dinv[col]*acc + b1[lane];
  h1s[threadIdx.x] = fmaxf(y, 0.f);
  __syncthreads();
  const float* hrow = h1s + col4*64;               // broadcast LDS reads
  float s = 0.f;
  #pragma unroll 8
  for (int h = 0; h < 64; h++) s += hrow[h]*W2[h*64 + lane];
  v2[(size_t)col*64 + lane] = dinv[col]*s;
}

// ---------------------------------------------------------------- FUSED layer2 agg + lstmpre
__global__ __launch_bounds__(256) void k_agg2pre(const float* __restrict__ v,
                                                 const int* __restrict__ cnt,
                                                 const uint16_t* __restrict__ idx,
                                                 const float* __restrict__ dinv,
                                                 const float* __restrict__ m,
                                                 const float* __restrict__ b2,
                                                 const float* __restrict__ Wih,
                                                 const float* __restrict__ bih,
                                                 const float* __restrict__ bhh,
                                                 float* __restrict__ P4){
  __shared__ float h2s[256];            // 4 cols × 64
  const int col4 = threadIdx.x >> 6;
  const int col = blockIdx.x*4 + col4;
  const int lane = threadIdx.x & 63;
  int c = cnt[col]; if (c > CAP_) c = CAP_;
  const int tbase = col & ~2047;
  const uint16_t* lst = idx + (size_t)col*CAP_;
  float acc = v[(size_t)col*64 + lane];            // self-loop
  int i = 0;
  for (; i + 4 <= c; i += 4){
    ushort4 s4 = *(const ushort4*)(lst + i);
    float a0 = v[((size_t)tbase + s4.x)*64 + lane];
    float a1 = v[((size_t)tbase + s4.y)*64 + lane];
    float a2 = v[((size_t)tbase + s4.z)*64 + lane];
    float a3 = v[((size_t)tbase + s4.w)*64 + lane];
    acc += (a0 + a1) + (a2 + a3);
  }
  for (; i < c; i++) acc += v[((size_t)tbase + lst[i])*64 + lane];
  float y = dinv[col]*acc + b2[lane];
  h2s[threadIdx.x] = m[col]*y;
  __syncthreads();
  #pragma unroll
  for (int o = threadIdx.x; o < 512; o += 256){
    const int cc = o >> 7;                         // 0..3
    const int j  = o & 127;
    const int tn = blockIdx.x*4 + cc;
    const v4* hrow = (const v4*)(h2s + cc*64);     // broadcast LDS b128 reads
    const v4* wr = (const v4*)(Wih + j*64);
    float a0 = bih[j] + bhh[j], a1 = 0.f, a2 = 0.f, a3 = 0.f;
    #pragma unroll
    for (int q = 0; q < 16; q++){
      v4 hv = hrow[q], wv = wr[q];
      a0 = fmaf(wv.x, hv.x, a0);
      a1 = fmaf(wv.y, hv.y, a1);
      a2 = fmaf(wv.z, hv.z, a2);
      a3 = fmaf(wv.w, hv.w, a3);
    }
    const int dst = (j & 31)*4 + (j >> 5);         // interleaved {i,f,g,o}
    P4[(size_t)tn*128 + dst] = (a0 + a1) + (a2 + a3);
  }
}

// ---------------------------------------------------------------- LSTM scan: 16 chains, 1 wave each (exact R8)
__global__ __attribute__((amdgpu_flat_work_group_size(64,64), amdgpu_waves_per_eu(1,1)))
void k_lstm(const float* __restrict__ P4,
            const float* __restrict__ Whh,
            float* __restrict__ L64){
  const int t = blockIdx.x;       // chain 0..15
  const int l = threadIdx.x;      // 0..63
  const int c4 = l & 15, q = l >> 4;
  const int j = l & 31;
#define LB(B) f16x8 b##B; { const float* wr = Whh + (size_t)(16*B + c4)*32 + 8*q; \
    f16x8 tmp; tmp[0]=(_Float16)wr[0]; tmp[1]=(_Float16)wr[1]; tmp[2]=(_Float16)wr[2]; \
    tmp[3]=(_Float16)wr[3]; tmp[4]=(_Float16)wr[4]; tmp[5]=(_Float16)wr[5]; \
    tmp[6]=(_Float16)wr[6]; tmp[7]=(_Float16)wr[7]; b##B = tmp; } asm("" : "+v"(b##B));
  LB(0) LB(1) LB(2) LB(3) LB(4) LB(5) LB(6) LB(7)
#undef LB
  __shared__ __align__(16) _Float16 hs[32];
  hs[j] = (_Float16)0.f;
  const float4* Pt = (const float4*)P4 + (size_t)t*N_*32 + j;
  float* Lt = L64 + (size_t)t*N_*64;
  float c = 0.f;
  const f32x4 zero = {0.f, 0.f, 0.f, 0.f};
  const bool hiq = (l & 16) != 0;
  float4 p0 = Pt[0], p1 = Pt[32];
  for (int n = 0; n < N_; n++){
    float4 cur = p0; p0 = p1;
    int np = (n + 2 < N_) ? (n + 2) : (N_ - 1);
    p1 = Pt[(size_t)np*32];
    f16x8 af = *(const f16x8*)(hs + 8*q);          // ds_read_b128
    f32x4 d0 = __builtin_amdgcn_mfma_f32_16x16x32_f16(af, b0, zero, 0, 0, 0);
    f32x4 d1 = __builtin_amdgcn_mfma_f32_16x16x32_f16(af, b1, zero, 0, 0, 0);
    f32x4 d2 = __builtin_amdgcn_mfma_f32_16x16x32_f16(af, b2, zero, 0, 0, 0);
    f32x4 d3 = __builtin_amdgcn_mfma_f32_16x16x32_f16(af, b3, zero, 0, 0, 0);
    f32x4 d4 = __builtin_amdgcn_mfma_f32_16x16x32_f16(af, b4, zero, 0, 0, 0);
    f32x4 d5 = __builtin_amdgcn_mfma_f32_16x16x32_f16(af, b5, zero, 0, 0, 0);
    f32x4 d6 = __builtin_amdgcn_mfma_f32_16x16x32_f16(af, b6, zero, 0, 0, 0);
    f32x4 d7 = __builtin_amdgcn_mfma_f32_16x16x32_f16(af, b7, zero, 0, 0, 0);
    float gi = cur.x + (hiq ? d1[0] : d0[0]);
    float gf = cur.y + (hiq ? d3[0] : d2[0]);
    float gg = cur.z + (hiq ? d5[0] : d4[0]);
    float go = cur.w + (hiq ? d7[0] : d6[0]);
    float iv = fsig(gi);
    float fv = fsig(gf);
    float gv = fmaf(2.0f, fsig(2.0f*gg), -1.0f);   // tanh
    float ov = fsig(go);
    c = fmaf(fv, c, iv*gv);
    float th = fmaf(2.0f, fsig(2.0f*c), -1.0f);    // tanh(c)
    float hn = ov*th;
    hs[j] = (_Float16)hn;                          // ds_write_b16
    Lt[n*64 + l] = hn;                             // full-wave store
  }
}

// ---------------------------------------------------------------- FUSED score + softmax attention pool
__global__ __launch_bounds__(256) void k_attn(const float* __restrict__ L64,
                                              const float* __restrict__ Wa,
                                              float* __restrict__ out){
  __shared__ float sLDS[128];           // 8 nodes × 16 scores
  const int tid = threadIdx.x;
  const int sub = tid >> 5, k = tid & 31;
  const int n = blockIdx.x*8 + sub;
  if (k < 16){
    const int t = k;
    const float4* row = (const float4*)(L64 + ((size_t)(t << 11) + n)*64);
    const float4* wa4 = (const float4*)Wa;
    float s = 0.f;
    #pragma unroll
    for (int qq = 0; qq < 8; qq++){
      float4 hv = row[qq], wv = wa4[qq];
      s += hv.x*wv.x + hv.y*wv.y + hv.z*wv.z + hv.w*wv.w;
    }
    sLDS[sub*16 + t] = s;
  }
  __syncthreads();
  float sc[16]; float mx = -1e30f;
  #pragma unroll
  for (int t = 0; t < 16; t++){ float v = sLDS[sub*16 + t]; sc[t] = v; mx = fmaxf(mx, v); }
  float sum = 0.f;
  #pragma unroll
  for (int t = 0; t < 16; t++){ float e = __expf(sc[t] - mx); sc[t] = e; sum += e; }
  const float inv = frcp(sum);
  float acc = 0.f;
  #pragma unroll
  for (int t = 0; t < 16; t++) acc += sc[t]*L64[((size_t)(t << 11) + n)*64 + k];
  out[n*32 + k] = acc*inv;
}

// ---------------------------------------------------------------- launch
extern "C" void kernel_launch(void* const* d_in, const int* in_sizes, int n_in,
                              void* d_out, int out_size, void* d_ws, size_t ws_size,
                              hipStream_t stream){
  (void)in_sizes; (void)n_in; (void)out_size; (void)ws_size;
  const float*   x   = (const float*)d_in[0];
  const float*   adj = (const float*)d_in[1];
  const uint8_t* ego = (const uint8_t*)d_in[2];
  const float*   W1  = (const float*)d_in[3];
  const float*   b1  = (const float*)d_in[4];
  const float*   W2  = (const float*)d_in[5];
  const float*   b2  = (const float*)d_in[6];
  const float*   Wih = (const float*)d_in[7];
  const float*   Whh = (const float*)d_in[8];
  const float*   bih = (const float*)d_in[9];
  const float*   bhh = (const float*)d_in[10];
  const float*   Wa  = (const float*)d_in[11];
  // d_in[12] = ba: softmax is shift-invariant, unused
  float* out = (float*)d_out;
  char* ws = (char*)d_ws;

  float*    m      = (float*)(ws);                  // 128 KB
  float*    dinv   = (float*)(ws + 131072);         // 128 KB
  int*      cnt    = (int*)  (ws + 262144);         // 128 KB
  uint16_t* idx    = (uint16_t*)(ws + 393216);      // 6 MB   (end 6,684,672)
  float*    v2     = (float*)(ws + 6684672);        // 8 MB   (v2; later reused as L64)
  float*    P4     = (float*)(ws + 15073280);       // 16 MB  (end 31,850,496)
  float*    L64    = v2;                            // v2 dead after k_agg2pre

  k_mask    <<<16,   256, 0, stream>>>(ego, m, cnt);
  k_sparsify<<<1024, 256, 0, stream>>>(adj, m, cnt, idx);
  k_dinv    <<<128,  256, 0, stream>>>(cnt, m, dinv);
  k_gcn1v2  <<<8192, 256, 0, stream>>>(x, W1, b1, W2, cnt, idx, dinv, v2);
  k_agg2pre <<<8192, 256, 0, stream>>>(v2, cnt, idx, dinv, m, b2, Wih, bih, bhh, P4);
  k_lstm    <<<16,   64,  0, stream>>>(P4, Whh, L64);
  k_attn    <<<256,  256, 0, stream>>>(L64, Wa, out);
}